// Round 10
// baseline (318.893 us; speedup 1.0000x reference)
//
#include <hip/hip_runtime.h>
#include <hip/hip_fp16.h>

// GCN 2-layer, CSR-gather, fp16 storage / fp32 math, MFMA GEMMs. R10.
// R9 lesson: per-dispatch gap ~4us (2 removed dispatches -> -7.7us), so the
// unattributed ~180us lives in sub-top-5 kernels (gath2 + CSR chain), not
// gaps. Also: fused gather runs 2.33 TB/s vs the IDENTICAL access pattern at
// 3.55 TB/s standalone (R1 k_gath1, same occupancy) — fused structure costs
// ~35% gather BW for reasons the imbalance model does NOT explain. R10:
// split back to the proven shapes, regain visibility:
//   k_histwt : edge histogram || weight transpose
//   k_scanT  : column scan -> startOff, btot
//   k_scatB  : redundant LDS scan of btot + edge scatter (blk0 publishes)
//   k_fillb  : deg/rowptr/dinv + srcIdx + y=half(x*dinv)
//   k_gath1  : R1's exact 62us gather (wave-per-node, 2-deep) -> aggX
//   k_gemm12 : GEMM1(relu,b1)+GEMM2(*dinv) fused, wave-private LDS, 0 barriers
//   k_gath2  : layer-2 gather -> out
// 7 dispatches, no global atomics, no device barriers.

constexpr int NN = 100000;
constexpr int NE = 1600000;
constexpr int BSH = 7;
constexpr int NB = (NN + 127) >> BSH;   // 782
constexpr int NBLK = 256;
constexpr int EPB = NE / NBLK;          // 6250
constexpr int TSTR = 784;

typedef _Float16 f16x8 __attribute__((ext_vector_type(8)));
typedef float f32x4 __attribute__((ext_vector_type(4)));

// ---- histogram (blocks 0..255) + weight transpose (blocks 256..351) ----
__global__ __launch_bounds__(256) void k_histwt(const int* __restrict__ cols,
                                                int* __restrict__ table,
                                                const float* __restrict__ W1,
                                                const float* __restrict__ W2,
                                                __half* __restrict__ Wt1,
                                                __half* __restrict__ Wt2) {
  if (blockIdx.x < NBLK) {
    __shared__ int cnt[NB];
    for (int i = threadIdx.x; i < NB; i += 256) cnt[i] = 0;
    __syncthreads();
    int base = blockIdx.x * EPB;
    for (int i = threadIdx.x; i < EPB; i += 256)
      atomicAdd(&cnt[cols[base + i] >> BSH], 1);
    __syncthreads();
    for (int i = threadIdx.x; i < NB; i += 256)
      table[blockIdx.x * TSTR + i] = cnt[i];
  } else {
    int i = (blockIdx.x - NBLK) * 256 + threadIdx.x;  // 24576 = 16384 + 8192
    if (i < 16384) {
      int k = i >> 7, n = i & 127;
      Wt1[n * 128 + k] = __float2half(W1[i]);
    } else {
      int j = i - 16384;
      int k = j >> 6, n = j & 63;
      Wt2[n * 128 + k] = __float2half(W2[j]);
    }
  }
}

// ------- scan table columns over blocks: startOff + bucket totals ------------
__global__ __launch_bounds__(256) void k_scanT(const int* __restrict__ table,
                                               int* __restrict__ startOff,
                                               int* __restrict__ btot) {
  __shared__ int s[256];
  int b = blockIdx.x, t = threadIdx.x;
  int v = table[t * TSTR + b];
  s[t] = v;
  __syncthreads();
  for (int off = 1; off < 256; off <<= 1) {
    int tmp = (t >= off) ? s[t - off] : 0;
    __syncthreads();
    s[t] += tmp;
    __syncthreads();
  }
  startOff[t * TSTR + b] = s[t] - v;
  if (t == 255) btot[b] = s[t];
}

// ---- per-block LDS scan of btot (redundant, proven) + edge scatter ----------
__global__ __launch_bounds__(256) void k_scatB(const int* __restrict__ rows,
                                               const int* __restrict__ cols,
                                               const int* __restrict__ startOff,
                                               const int* __restrict__ btot,
                                               int* __restrict__ bucketBase,
                                               unsigned* __restrict__ binned) {
  __shared__ int bb[NB];
  __shared__ int s[256];
  __shared__ int scnt[NB];
  int tid = threadIdx.x;
  int base4 = tid * 4;
  int d0 = (base4 + 0 < NB) ? btot[base4 + 0] : 0;
  int d1 = (base4 + 1 < NB) ? btot[base4 + 1] : 0;
  int d2 = (base4 + 2 < NB) ? btot[base4 + 2] : 0;
  int d3 = (base4 + 3 < NB) ? btot[base4 + 3] : 0;
  int tsum = d0 + d1 + d2 + d3;
  s[tid] = tsum;
  __syncthreads();
  for (int off = 1; off < 256; off <<= 1) {
    int tmp = (tid >= off) ? s[tid - off] : 0;
    __syncthreads();
    s[tid] += tmp;
    __syncthreads();
  }
  int ex = s[tid] - tsum;
  if (base4 + 0 < NB) bb[base4 + 0] = ex;
  if (base4 + 1 < NB) bb[base4 + 1] = ex + d0;
  if (base4 + 2 < NB) bb[base4 + 2] = ex + d0 + d1;
  if (base4 + 3 < NB) bb[base4 + 3] = ex + d0 + d1 + d2;
  __syncthreads();
  if (blockIdx.x == 0)
    for (int i = tid; i < NB; i += 256) bucketBase[i] = bb[i];
  for (int i = tid; i < NB; i += 256)
    scnt[i] = bb[i] + startOff[blockIdx.x * TSTR + i];
  __syncthreads();
  int base = blockIdx.x * EPB;
  for (int i = tid; i < EPB; i += 256) {
    int c = cols[base + i];
    int r = rows[base + i];
    int pos = atomicAdd(&scnt[c >> BSH], 1);
    binned[pos] = ((unsigned)r << BSH) | (unsigned)(c & 127);
  }
}

// ------- per-bucket fill: deg/rowptr/dinv + node-grouped srcIdx + y ----------
__global__ __launch_bounds__(256) void k_fillb(const unsigned* __restrict__ binned,
                                               const int* __restrict__ bucketBase,
                                               const int* __restrict__ btot,
                                               int* __restrict__ rowptr,
                                               int* __restrict__ deg,
                                               float* __restrict__ dinv,
                                               int* __restrict__ srcIdx,
                                               const float4* __restrict__ x4,
                                               float2* __restrict__ y8) {
  __shared__ int cnt[128];
  __shared__ int sc[128];
  __shared__ int rp[128];
  __shared__ float sdv[128];
  int b = blockIdx.x;
  int nb0 = b << BSH;
  int nn = min(128, NN - nb0);
  int tid = threadIdx.x;
  if (tid < 128) cnt[tid] = 0;
  __syncthreads();
  int ebeg = bucketBase[b];
  int eend = ebeg + btot[b];
  for (int p = ebeg + tid; p < eend; p += 256)
    atomicAdd(&cnt[binned[p] & 127], 1);
  __syncthreads();
  int v = (tid < 128) ? cnt[tid] : 0;
  if (tid < 128) sc[tid] = v;
  __syncthreads();
  for (int off = 1; off < 128; off <<= 1) {
    int tmp = (tid < 128 && tid >= off) ? sc[tid - off] : 0;
    __syncthreads();
    if (tid < 128) sc[tid] += tmp;
    __syncthreads();
  }
  if (tid < 128) {
    int ex = sc[tid] - v;
    rp[tid] = ebeg + ex;
    float dv = rsqrtf((float)v + 1.0f);
    sdv[tid] = dv;
    if (tid < nn) {
      rowptr[nb0 + tid] = ebeg + ex;
      deg[nb0 + tid] = v;
      dinv[nb0 + tid] = dv;
    }
    cnt[tid] = 0;
  }
  __syncthreads();
  for (int p = ebeg + tid; p < eend; p += 256) {
    unsigned pk = binned[p];
    int cl = pk & 127;
    int local = atomicAdd(&cnt[cl], 1);
    srcIdx[rp[cl] + local] = (int)(pk >> BSH);
  }
  // fused k_y: this bucket's x rows -> y = half(x*dinv)
  int tot = nn << 5;
  const float4* xb = x4 + ((size_t)nb0 << 5);
  float2* yb = y8 + ((size_t)nb0 << 5);
  for (int i = tid; i < tot; i += 256) {
    float sfac = sdv[i >> 5];
    float4 vv = xb[i];
    union { __half2 h[2]; float2 f; } u;
    u.h[0] = __floats2half2_rn(vv.x * sfac, vv.y * sfac);
    u.h[1] = __floats2half2_rn(vv.z * sfac, vv.w * sfac);
    yb[i] = u.f;
  }
}

// ---------------- gather-aggregate, width 128 half (wave per node) -----------
// R1's proven 62.2us / 3.55 TB/s kernel, verbatim: 16 lanes cover one 256B
// row -> 4 neighbor rows per load instruction, 2-deep unroll = 8 rows (2KB)
// in flight; cross-group shfl_xor butterfly combines once per node.
__global__ __launch_bounds__(256) void k_gath1(const __half* __restrict__ y,
                                               const int* __restrict__ rowptr,
                                               const int* __restrict__ deg,
                                               const int* __restrict__ srcIdx,
                                               const float* __restrict__ dinv,
                                               __half* __restrict__ agg) {
  int node = blockIdx.x * 4 + (threadIdx.x >> 6);
  if (node >= NN) return;
  int lane = threadIdx.x & 63;
  int g = lane >> 4;       // neighbor slot 0..3
  int c = lane & 15;       // column chunk: halfs [c*8, c*8+8)
  int d = deg[node];
  int p = rowptr[node];
  size_t coff = (size_t)c * 8;
  float acc[8];
#pragma unroll
  for (int i = 0; i < 8; i++) acc[i] = 0.0f;

  for (int base = 0; base < d; base += 64) {
    int cnt = min(64, d - base);
    int my = (lane < cnt) ? srcIdx[p + base + lane] : 0;
    int k = 0;
    for (; k + 8 <= cnt; k += 8) {           // 8 neighbors, 2 loads in flight
      int s0 = __shfl(my, k + g);
      int s1 = __shfl(my, k + 4 + g);
      f16x8 v0 = *reinterpret_cast<const f16x8*>(y + (size_t)s0 * 128 + coff);
      f16x8 v1 = *reinterpret_cast<const f16x8*>(y + (size_t)s1 * 128 + coff);
#pragma unroll
      for (int i = 0; i < 8; i++) acc[i] += (float)v0[i];
#pragma unroll
      for (int i = 0; i < 8; i++) acc[i] += (float)v1[i];
    }
    for (; k < cnt; k += 4) {                // remainder, predicated
      int idx = k + g;
      bool valid = idx < cnt;
      int s0 = __shfl(my, valid ? idx : 0);
      f16x8 v0 = *reinterpret_cast<const f16x8*>(y + (size_t)s0 * 128 + coff);
      if (valid) {
#pragma unroll
        for (int i = 0; i < 8; i++) acc[i] += (float)v0[i];
      }
    }
  }
#pragma unroll
  for (int i = 0; i < 8; i++) acc[i] += __shfl_xor(acc[i], 16);
#pragma unroll
  for (int i = 0; i < 8; i++) acc[i] += __shfl_xor(acc[i], 32);
  if (g == 0) {
    f16x8 sv = *reinterpret_cast<const f16x8*>(y + (size_t)node * 128 + coff);
    float sc = dinv[node];
    union { __half2 h[4]; float4 f; } o;
#pragma unroll
    for (int j = 0; j < 4; j++) {
      float a = (acc[2 * j]     + (float)sv[2 * j])     * sc;
      float b = (acc[2 * j + 1] + (float)sv[2 * j + 1]) * sc;
      o.h[j] = __floats2half2_rn(a, b);
    }
    *reinterpret_cast<float4*>(agg + (size_t)node * 128 + coff) = o.f;
  }
}

// ---- fused GEMM1(relu,b1) + GEMM2(*dinv): aggX -> z, wave-private, 0 barriers
// block = 64 rows, 4 waves; wave w owns rows [rowTop, rowTop+16). h1 staged in
// wave-private LDS then overwritten by the z tile (R3-proven same-buffer
// reuse: in-order per-wave DS pipe + compiler lgkmcnt). MFMA 16x16x32 f16.
// A frag: lane holds A[row=(l&15)][kc+(l>>4)*8+j]; C/D: reg i =
// C[(l>>4)*4+i][t*16+(l&15)]  (m89).
__global__ __launch_bounds__(256, 4) void k_gemm12(
    const __half* __restrict__ A, const __half* __restrict__ Wt1,
    const float* __restrict__ b1, const __half* __restrict__ Wt2,
    const float* __restrict__ dinv, __half* __restrict__ z) {
  __shared__ __align__(16) __half sH[4][16][136];
  const int w = threadIdx.x >> 6, l = threadIdx.x & 63;
  const int quad = l >> 4, m = l & 15;
  const int rowTop = blockIdx.x * 64 + w * 16;
  if (rowTop >= NN) return;  // NN%16==0: whole wave valid or invalid

  int arow = rowTop + m;     // rowTop+15 < NN guaranteed by the guard above
  const __half* ap = A + (size_t)arow * 128 + quad * 8;

  // GEMM1: h1 = relu(aggX @ W1 + b1), full 8 col tiles per wave
  f32x4 acc1[8];
#pragma unroll
  for (int t = 0; t < 8; t++) {
    float bv = b1[t * 16 + m];
    acc1[t] = (f32x4){bv, bv, bv, bv};
  }
#pragma unroll
  for (int kc = 0; kc < 128; kc += 32) {
    f16x8 a = *reinterpret_cast<const f16x8*>(ap + kc);
#pragma unroll
    for (int t = 0; t < 8; t++) {
      f16x8 b = *reinterpret_cast<const f16x8*>(
          Wt1 + (size_t)(t * 16 + m) * 128 + kc + quad * 8);
      acc1[t] = __builtin_amdgcn_mfma_f32_16x16x32_f16(a, b, acc1[t], 0, 0, 0);
    }
  }
#pragma unroll
  for (int t = 0; t < 8; t++)
#pragma unroll
    for (int i = 0; i < 4; i++)
      sH[w][quad * 4 + i][t * 16 + m] = __float2half(fmaxf(acc1[t][i], 0.0f));

  // GEMM2: z = (h1 @ W2) * dinv[row], 4 col tiles
  f16x8 hfrag[4];
#pragma unroll
  for (int kk = 0; kk < 4; kk++)
    hfrag[kk] = *reinterpret_cast<const f16x8*>(&sH[w][m][kk * 32 + quad * 8]);
  f32x4 acc2[4];
#pragma unroll
  for (int t = 0; t < 4; t++) acc2[t] = (f32x4){0.f, 0.f, 0.f, 0.f};
#pragma unroll
  for (int kk = 0; kk < 4; kk++) {
#pragma unroll
    for (int t = 0; t < 4; t++) {
      f16x8 b = *reinterpret_cast<const f16x8*>(
          Wt2 + (size_t)(t * 16 + m) * 128 + kk * 32 + quad * 8);
      acc2[t] = __builtin_amdgcn_mfma_f32_16x16x32_f16(hfrag[kk], b, acc2[t], 0, 0, 0);
    }
  }
  float rs[4];
#pragma unroll
  for (int i = 0; i < 4; i++) rs[i] = dinv[rowTop + quad * 4 + i];
  // overwrite sH[w] with the z tile (hfrag already in VGPRs)
#pragma unroll
  for (int t = 0; t < 4; t++)
#pragma unroll
    for (int i = 0; i < 4; i++)
      sH[w][quad * 4 + i][t * 16 + m] = __float2half(acc2[t][i] * rs[i]);

  // store 16 rows x 64 halves (128B/row): 64 lanes x 2 float4
#pragma unroll
  for (int rep = 0; rep < 2; rep++) {
    int idx = rep * 64 + l;
    int r = idx >> 3, cc = idx & 7;
    *reinterpret_cast<float4*>(z + (size_t)(rowTop + r) * 64 + cc * 8) =
        *reinterpret_cast<const float4*>(&sH[w][r][cc * 8]);
  }
}

// ---------------- gather-aggregate, width 64 half (wave per node) ------------
__global__ __launch_bounds__(256) void k_gath2(const __half* __restrict__ z,
                                               const int* __restrict__ rowptr,
                                               const int* __restrict__ deg,
                                               const int* __restrict__ srcIdx,
                                               const float* __restrict__ dinv,
                                               const float* __restrict__ b2,
                                               float* __restrict__ out) {
  int node = blockIdx.x * 4 + (threadIdx.x >> 6);
  if (node >= NN) return;
  int lane = threadIdx.x & 63;
  int g = lane >> 3;
  int c = lane & 7;
  int d = deg[node];
  int p = rowptr[node];
  size_t coff = (size_t)c * 8;
  float acc[8];
#pragma unroll
  for (int i = 0; i < 8; i++) acc[i] = 0.0f;

  for (int base = 0; base < d; base += 64) {
    int cnt = min(64, d - base);
    int my = (lane < cnt) ? srcIdx[p + base + lane] : 0;
    int k = 0;
    for (; k + 16 <= cnt; k += 16) {         // 16 neighbors, 2 loads in flight
      int s0 = __shfl(my, k + g);
      int s1 = __shfl(my, k + 8 + g);
      f16x8 v0 = *reinterpret_cast<const f16x8*>(z + (size_t)s0 * 64 + coff);
      f16x8 v1 = *reinterpret_cast<const f16x8*>(z + (size_t)s1 * 64 + coff);
#pragma unroll
      for (int i = 0; i < 8; i++) acc[i] += (float)v0[i];
#pragma unroll
      for (int i = 0; i < 8; i++) acc[i] += (float)v1[i];
    }
    for (; k < cnt; k += 8) {                // remainder, predicated
      int idx = k + g;
      bool valid = idx < cnt;
      int s0 = __shfl(my, valid ? idx : 0);
      f16x8 v0 = *reinterpret_cast<const f16x8*>(z + (size_t)s0 * 64 + coff);
      if (valid) {
#pragma unroll
        for (int i = 0; i < 8; i++) acc[i] += (float)v0[i];
      }
    }
  }
#pragma unroll
  for (int i = 0; i < 8; i++) acc[i] += __shfl_xor(acc[i], 8);
#pragma unroll
  for (int i = 0; i < 8; i++) acc[i] += __shfl_xor(acc[i], 16);
#pragma unroll
  for (int i = 0; i < 8; i++) acc[i] += __shfl_xor(acc[i], 32);
  if (g == 0) {
    f16x8 sv = *reinterpret_cast<const f16x8*>(z + (size_t)node * 64 + coff);
    float s = dinv[node];
    const float4* b4 = reinterpret_cast<const float4*>(b2);
    float4 bv0 = b4[2 * c], bv1 = b4[2 * c + 1];
    float4 o0, o1;
    o0.x = (acc[0] + (float)sv[0]) * s + bv0.x;
    o0.y = (acc[1] + (float)sv[1]) * s + bv0.y;
    o0.z = (acc[2] + (float)sv[2]) * s + bv0.z;
    o0.w = (acc[3] + (float)sv[3]) * s + bv0.w;
    o1.x = (acc[4] + (float)sv[4]) * s + bv1.x;
    o1.y = (acc[5] + (float)sv[5]) * s + bv1.y;
    o1.z = (acc[6] + (float)sv[6]) * s + bv1.z;
    o1.w = (acc[7] + (float)sv[7]) * s + bv1.w;
    float4* op = reinterpret_cast<float4*>(out + (size_t)node * 64 + coff);
    op[0] = o0;
    op[1] = o1;
  }
}

extern "C" void kernel_launch(void* const* d_in, const int* in_sizes, int n_in,
                              void* d_out, int out_size, void* d_ws, size_t ws_size,
                              hipStream_t stream) {
  const float* x  = (const float*)d_in[0];
  const int*   ei = (const int*)d_in[1];  // [2, NE] row-major
  const int* rows = ei;
  const int* cols = ei + NE;
  const float* W1 = (const float*)d_in[3];
  const float* b1 = (const float*)d_in[4];
  const float* W2 = (const float*)d_in[5];
  const float* b2 = (const float*)d_in[6];
  float* out = (float*)d_out;

  char* base = (char*)d_ws;
  constexpr size_t MB = 1 << 20;
  int*      deg       = (int*)(base + 0 * MB);
  int*      rowptr    = (int*)(base + 1 * MB);
  float*    dinv      = (float*)(base + 2 * MB);
  int*      btot      = (int*)(base + 3 * MB);
  int*      bucketBase= (int*)(base + 3 * MB + 16 * 1024);
  __half*   Wt1       = (__half*)(base + 3 * MB + 64 * 1024);
  __half*   Wt2       = (__half*)(base + 3 * MB + 128 * 1024);
  int*      table     = (int*)(base + 4 * MB);
  int*      startOff  = (int*)(base + 5 * MB);
  unsigned* binned    = (unsigned*)(base + 6 * MB);
  int*      srcIdx    = (int*)(base + 13 * MB);
  __half*   y         = (__half*)(base + 20 * MB);    // 25.6 MB
  __half*   aggx      = (__half*)(base + 46 * MB);    // 25.6 MB
  __half*   z         = (__half*)(base + 72 * MB);    // 12.8 MB

  k_histwt<<<NBLK + 96, 256, 0, stream>>>(cols, table, W1, W2, Wt1, Wt2);
  k_scanT<<<NB, 256, 0, stream>>>(table, startOff, btot);
  k_scatB<<<NBLK, 256, 0, stream>>>(rows, cols, startOff, btot, bucketBase,
                                    binned);
  k_fillb<<<NB, 256, 0, stream>>>(binned, bucketBase, btot, rowptr, deg, dinv,
                                  srcIdx, (const float4*)x, (float2*)y);
  k_gath1<<<(NN + 3) / 4, 256, 0, stream>>>(y, rowptr, deg, srcIdx, dinv, aggx);
  k_gemm12<<<(NN + 63) / 64, 256, 0, stream>>>(aggx, Wt1, b1, Wt2, dinv, z);
  k_gath2<<<(NN + 3) / 4, 256, 0, stream>>>(z, rowptr, deg, srcIdx, dinv, b2, out);
}

// Round 11
// 284.311 us; speedup vs baseline: 1.1216x; 1.1216x over previous
//
#include <hip/hip_runtime.h>
#include <hip/hip_fp16.h>

// GCN 2-layer, CSR-gather, fp16 storage / fp32 math, MFMA GEMMs. R11.
// R10 lesson: split GEMM kernel = 48us (latency-bound, 5x roofline) vs
// fused GEMM's +27us -> R9 fused structure wins; reverted. R11 = R9 +
// software-pipelined gather in k_fused: per wave, the 4 node headers
// (deg/rowptr/dinv) are preloaded by lanes 0-3 and shfl-broadcast (kills 3
// of 4 header bubbles); node i+1's first srcIdx chunk is issued before node
// i's accumulate loop (latency hides under node i's gather loads); self-row
// load hoisted. Poisson(16) degrees -> d<=64 single-chunk fast path ~100%.
//   k_histwt : edge histogram || weight transpose
//   k_scanT  : column scan -> startOff, btot
//   k_scatB  : redundant LDS scan of btot + edge scatter (blk0 publishes)
//   k_fillb  : deg/rowptr/dinv + srcIdx + y=half(x*dinv)
//   k_fused  : pipelined gather + GEMM1(relu,b1) + GEMM2(*dinv), 16-row tile
//   k_gath2  : layer-2 gather -> out (4-deep MLP)
// 6 dispatches, no global atomics, no device barriers.

constexpr int NN = 100000;
constexpr int NE = 1600000;
constexpr int BSH = 7;
constexpr int NB = (NN + 127) >> BSH;   // 782
constexpr int NBLK = 256;
constexpr int EPB = NE / NBLK;          // 6250
constexpr int TSTR = 784;

typedef _Float16 f16x8 __attribute__((ext_vector_type(8)));
typedef float f32x4 __attribute__((ext_vector_type(4)));

// ---- histogram (blocks 0..255) + weight transpose (blocks 256..351) ----
__global__ __launch_bounds__(256) void k_histwt(const int* __restrict__ cols,
                                                int* __restrict__ table,
                                                const float* __restrict__ W1,
                                                const float* __restrict__ W2,
                                                __half* __restrict__ Wt1,
                                                __half* __restrict__ Wt2) {
  if (blockIdx.x < NBLK) {
    __shared__ int cnt[NB];
    for (int i = threadIdx.x; i < NB; i += 256) cnt[i] = 0;
    __syncthreads();
    int base = blockIdx.x * EPB;
    for (int i = threadIdx.x; i < EPB; i += 256)
      atomicAdd(&cnt[cols[base + i] >> BSH], 1);
    __syncthreads();
    for (int i = threadIdx.x; i < NB; i += 256)
      table[blockIdx.x * TSTR + i] = cnt[i];
  } else {
    int i = (blockIdx.x - NBLK) * 256 + threadIdx.x;  // 24576 = 16384 + 8192
    if (i < 16384) {
      int k = i >> 7, n = i & 127;
      Wt1[n * 128 + k] = __float2half(W1[i]);
    } else {
      int j = i - 16384;
      int k = j >> 6, n = j & 63;
      Wt2[n * 128 + k] = __float2half(W2[j]);
    }
  }
}

// ------- scan table columns over blocks: startOff + bucket totals ------------
__global__ __launch_bounds__(256) void k_scanT(const int* __restrict__ table,
                                               int* __restrict__ startOff,
                                               int* __restrict__ btot) {
  __shared__ int s[256];
  int b = blockIdx.x, t = threadIdx.x;
  int v = table[t * TSTR + b];
  s[t] = v;
  __syncthreads();
  for (int off = 1; off < 256; off <<= 1) {
    int tmp = (t >= off) ? s[t - off] : 0;
    __syncthreads();
    s[t] += tmp;
    __syncthreads();
  }
  startOff[t * TSTR + b] = s[t] - v;
  if (t == 255) btot[b] = s[t];
}

// ---- per-block LDS scan of btot (redundant, proven) + edge scatter ----------
__global__ __launch_bounds__(256) void k_scatB(const int* __restrict__ rows,
                                               const int* __restrict__ cols,
                                               const int* __restrict__ startOff,
                                               const int* __restrict__ btot,
                                               int* __restrict__ bucketBase,
                                               unsigned* __restrict__ binned) {
  __shared__ int bb[NB];
  __shared__ int s[256];
  __shared__ int scnt[NB];
  int tid = threadIdx.x;
  int base4 = tid * 4;
  int d0 = (base4 + 0 < NB) ? btot[base4 + 0] : 0;
  int d1 = (base4 + 1 < NB) ? btot[base4 + 1] : 0;
  int d2 = (base4 + 2 < NB) ? btot[base4 + 2] : 0;
  int d3 = (base4 + 3 < NB) ? btot[base4 + 3] : 0;
  int tsum = d0 + d1 + d2 + d3;
  s[tid] = tsum;
  __syncthreads();
  for (int off = 1; off < 256; off <<= 1) {
    int tmp = (tid >= off) ? s[tid - off] : 0;
    __syncthreads();
    s[tid] += tmp;
    __syncthreads();
  }
  int ex = s[tid] - tsum;
  if (base4 + 0 < NB) bb[base4 + 0] = ex;
  if (base4 + 1 < NB) bb[base4 + 1] = ex + d0;
  if (base4 + 2 < NB) bb[base4 + 2] = ex + d0 + d1;
  if (base4 + 3 < NB) bb[base4 + 3] = ex + d0 + d1 + d2;
  __syncthreads();
  if (blockIdx.x == 0)
    for (int i = tid; i < NB; i += 256) bucketBase[i] = bb[i];
  for (int i = tid; i < NB; i += 256)
    scnt[i] = bb[i] + startOff[blockIdx.x * TSTR + i];
  __syncthreads();
  int base = blockIdx.x * EPB;
  for (int i = tid; i < EPB; i += 256) {
    int c = cols[base + i];
    int r = rows[base + i];
    int pos = atomicAdd(&scnt[c >> BSH], 1);
    binned[pos] = ((unsigned)r << BSH) | (unsigned)(c & 127);
  }
}

// ------- per-bucket fill: deg/rowptr/dinv + node-grouped srcIdx + y ----------
__global__ __launch_bounds__(256) void k_fillb(const unsigned* __restrict__ binned,
                                               const int* __restrict__ bucketBase,
                                               const int* __restrict__ btot,
                                               int* __restrict__ rowptr,
                                               int* __restrict__ deg,
                                               float* __restrict__ dinv,
                                               int* __restrict__ srcIdx,
                                               const float4* __restrict__ x4,
                                               float2* __restrict__ y8) {
  __shared__ int cnt[128];
  __shared__ int sc[128];
  __shared__ int rp[128];
  __shared__ float sdv[128];
  int b = blockIdx.x;
  int nb0 = b << BSH;
  int nn = min(128, NN - nb0);
  int tid = threadIdx.x;
  if (tid < 128) cnt[tid] = 0;
  __syncthreads();
  int ebeg = bucketBase[b];
  int eend = ebeg + btot[b];
  for (int p = ebeg + tid; p < eend; p += 256)
    atomicAdd(&cnt[binned[p] & 127], 1);
  __syncthreads();
  int v = (tid < 128) ? cnt[tid] : 0;
  if (tid < 128) sc[tid] = v;
  __syncthreads();
  for (int off = 1; off < 128; off <<= 1) {
    int tmp = (tid < 128 && tid >= off) ? sc[tid - off] : 0;
    __syncthreads();
    if (tid < 128) sc[tid] += tmp;
    __syncthreads();
  }
  if (tid < 128) {
    int ex = sc[tid] - v;
    rp[tid] = ebeg + ex;
    float dv = rsqrtf((float)v + 1.0f);
    sdv[tid] = dv;
    if (tid < nn) {
      rowptr[nb0 + tid] = ebeg + ex;
      deg[nb0 + tid] = v;
      dinv[nb0 + tid] = dv;
    }
    cnt[tid] = 0;
  }
  __syncthreads();
  for (int p = ebeg + tid; p < eend; p += 256) {
    unsigned pk = binned[p];
    int cl = pk & 127;
    int local = atomicAdd(&cnt[cl], 1);
    srcIdx[rp[cl] + local] = (int)(pk >> BSH);
  }
  // fused k_y: this bucket's x rows -> y = half(x*dinv)
  int tot = nn << 5;
  const float4* xb = x4 + ((size_t)nb0 << 5);
  float2* yb = y8 + ((size_t)nb0 << 5);
  for (int i = tid; i < tot; i += 256) {
    float sfac = sdv[i >> 5];
    float4 vv = xb[i];
    union { __half2 h[2]; float2 f; } u;
    u.h[0] = __floats2half2_rn(vv.x * sfac, vv.y * sfac);
    u.h[1] = __floats2half2_rn(vv.z * sfac, vv.w * sfac);
    yb[i] = u.f;
  }
}

// ---- fused gather + GEMM1(+bias,relu) + GEMM2(+dinv), pipelined gather ------
// block = 16 rows, 4 waves, grid = NN/16 = 6250. Wave w gathers rows
// [w*4,w*4+4): whole wave on ONE node, 4 slots (quad) x 16-lane 256B chunks,
// 4 loads in flight. R11 pipeline: all 4 node headers preloaded by lanes 0-3
// + shfl broadcast; next node's first srcIdx chunk issued before current
// node's accumulate; self-row load hoisted. GEMM1: wave w -> col tiles
// 2w,2w+1. GEMM2: wave w -> col tile w. MFMA 16x16x32 f16, fp32 acc.
__global__ __launch_bounds__(256, 8) void k_fused(
    const __half* __restrict__ y, const int* __restrict__ rowptr,
    const int* __restrict__ deg, const int* __restrict__ srcIdx,
    const float* __restrict__ dinv, const __half* __restrict__ Wt1,
    const float* __restrict__ b1, const __half* __restrict__ Wt2,
    __half* __restrict__ z) {
  __shared__ __align__(16) __half sA[16][136];
  __shared__ __align__(16) __half sB[16][136];
  const int w = threadIdx.x >> 6, l = threadIdx.x & 63;
  const int blk0 = blockIdx.x * 16;
  const int quad = l >> 4, m = l & 15;

  // ---- header preload: lanes 0-3 hold deg/rowptr/dinv of the 4 nodes ----
  int hd = 0, hp = 0;
  float hv = 0.0f;
  if (l < 4) {
    hd = deg[blk0 + w * 4 + l];
    hp = rowptr[blk0 + w * 4 + l];
    hv = dinv[blk0 + w * 4 + l];
  }
  int d = __shfl(hd, 0);
  int ptr = __shfl(hp, 0);
  // first chunk of node 0 issued before the loop
  int my = (l < min(d, 64)) ? srcIdx[ptr + l] : 0;

  for (int i = 0; i < 4; ++i) {
    const int node = blk0 + w * 4 + i;
    const int dn = (i < 3) ? __shfl(hd, i + 1) : 0;
    const int pn = (i < 3) ? __shfl(hp, i + 1) : 0;
    // prefetch next node's first chunk + this node's self row (independent)
    int myn = (i < 3 && l < min(dn, 64)) ? srcIdx[pn + l] : 0;
    f16x8 sv = *reinterpret_cast<const f16x8*>(y + (size_t)node * 128 + m * 8);

    float acc[8];
#pragma unroll
    for (int j = 0; j < 8; j++) acc[j] = 0.0f;

    // ---- fast path: chunk 0 (covers d<=64, ~100% of Poisson(16) nodes) ----
    {
      int cnt = min(d, 64);
      int k = 0;
      for (; k + 16 <= cnt; k += 16) {   // 16 neighbors, 4 loads in flight
        int s0 = __shfl(my, k + quad);
        int s1 = __shfl(my, k + 4 + quad);
        int s2 = __shfl(my, k + 8 + quad);
        int s3 = __shfl(my, k + 12 + quad);
        f16x8 v0 = *reinterpret_cast<const f16x8*>(y + (size_t)s0 * 128 + m * 8);
        f16x8 v1 = *reinterpret_cast<const f16x8*>(y + (size_t)s1 * 128 + m * 8);
        f16x8 v2 = *reinterpret_cast<const f16x8*>(y + (size_t)s2 * 128 + m * 8);
        f16x8 v3 = *reinterpret_cast<const f16x8*>(y + (size_t)s3 * 128 + m * 8);
#pragma unroll
        for (int j = 0; j < 8; j++) acc[j] += (float)v0[j];
#pragma unroll
        for (int j = 0; j < 8; j++) acc[j] += (float)v1[j];
#pragma unroll
        for (int j = 0; j < 8; j++) acc[j] += (float)v2[j];
#pragma unroll
        for (int j = 0; j < 8; j++) acc[j] += (float)v3[j];
      }
      for (; k + 8 <= cnt; k += 8) {     // 8 neighbors, 2 loads in flight
        int s0 = __shfl(my, k + quad);
        int s1 = __shfl(my, k + 4 + quad);
        f16x8 v0 = *reinterpret_cast<const f16x8*>(y + (size_t)s0 * 128 + m * 8);
        f16x8 v1 = *reinterpret_cast<const f16x8*>(y + (size_t)s1 * 128 + m * 8);
#pragma unroll
        for (int j = 0; j < 8; j++) acc[j] += (float)v0[j];
#pragma unroll
        for (int j = 0; j < 8; j++) acc[j] += (float)v1[j];
      }
      for (; k < cnt; k += 4) {          // remainder, predicated
        int idx = k + quad;
        bool valid = idx < cnt;
        int s0 = __shfl(my, valid ? idx : 0);
        f16x8 v0 = *reinterpret_cast<const f16x8*>(y + (size_t)s0 * 128 + m * 8);
        if (valid) {
#pragma unroll
          for (int j = 0; j < 8; j++) acc[j] += (float)v0[j];
        }
      }
    }
    // ---- rare tail: d > 64 ----
    for (int base = 64; base < d; base += 64) {
      int cnt = min(64, d - base);
      int mt = (l < cnt) ? srcIdx[ptr + base + l] : 0;
      int k = 0;
      for (; k + 8 <= cnt; k += 8) {
        int s0 = __shfl(mt, k + quad);
        int s1 = __shfl(mt, k + 4 + quad);
        f16x8 v0 = *reinterpret_cast<const f16x8*>(y + (size_t)s0 * 128 + m * 8);
        f16x8 v1 = *reinterpret_cast<const f16x8*>(y + (size_t)s1 * 128 + m * 8);
#pragma unroll
        for (int j = 0; j < 8; j++) acc[j] += (float)v0[j];
#pragma unroll
        for (int j = 0; j < 8; j++) acc[j] += (float)v1[j];
      }
      for (; k < cnt; k += 4) {
        int idx = k + quad;
        bool valid = idx < cnt;
        int s0 = __shfl(mt, valid ? idx : 0);
        f16x8 v0 = *reinterpret_cast<const f16x8*>(y + (size_t)s0 * 128 + m * 8);
        if (valid) {
#pragma unroll
          for (int j = 0; j < 8; j++) acc[j] += (float)v0[j];
        }
      }
    }

    // combine 4 slots (same columns in all slots)
#pragma unroll
    for (int j = 0; j < 8; j++) acc[j] += __shfl_xor(acc[j], 16);
#pragma unroll
    for (int j = 0; j < 8; j++) acc[j] += __shfl_xor(acc[j], 32);
    if (quad == 0) {
      float scn = __shfl(hv, i);
      f16x8 o;
#pragma unroll
      for (int j = 0; j < 8; j++)
        o[j] = (_Float16)((acc[j] + (float)sv[j]) * scn);
      *reinterpret_cast<f16x8*>(&sA[w * 4 + i][m * 8]) = o;
    }
    d = dn;
    ptr = pn;
    my = myn;
  }
  __syncthreads();

  // GEMM1: wave w -> col tiles 2w, 2w+1
  f16x8 afrag[4];
#pragma unroll
  for (int kk = 0; kk < 4; kk++)
    afrag[kk] = *reinterpret_cast<const f16x8*>(&sA[m][kk * 32 + quad * 8]);
  f32x4 acc1[2];
#pragma unroll
  for (int t = 0; t < 2; t++) {
    float bv = b1[(w * 2 + t) * 16 + m];
    acc1[t] = (f32x4){bv, bv, bv, bv};
  }
#pragma unroll
  for (int kk = 0; kk < 4; kk++) {
#pragma unroll
    for (int t = 0; t < 2; t++) {
      f16x8 b = *reinterpret_cast<const f16x8*>(
          Wt1 + (size_t)((w * 2 + t) * 16 + m) * 128 + kk * 32 + quad * 8);
      acc1[t] = __builtin_amdgcn_mfma_f32_16x16x32_f16(afrag[kk], b, acc1[t], 0, 0, 0);
    }
  }
#pragma unroll
  for (int t = 0; t < 2; t++)
#pragma unroll
    for (int i = 0; i < 4; i++)
      sB[quad * 4 + i][(w * 2 + t) * 16 + m] =
          __float2half(fmaxf(acc1[t][i], 0.0f));
  __syncthreads();

  // GEMM2: wave w -> col tile w
  f16x8 hfrag[4];
#pragma unroll
  for (int kk = 0; kk < 4; kk++)
    hfrag[kk] = *reinterpret_cast<const f16x8*>(&sB[m][kk * 32 + quad * 8]);
  f32x4 acc2 = (f32x4){0.f, 0.f, 0.f, 0.f};
#pragma unroll
  for (int kk = 0; kk < 4; kk++) {
    f16x8 b = *reinterpret_cast<const f16x8*>(
        Wt2 + (size_t)(w * 16 + m) * 128 + kk * 32 + quad * 8);
    acc2 = __builtin_amdgcn_mfma_f32_16x16x32_f16(hfrag[kk], b, acc2, 0, 0, 0);
  }
  float rs[4];
#pragma unroll
  for (int i = 0; i < 4; i++) rs[i] = dinv[blk0 + quad * 4 + i];
#pragma unroll
  for (int i = 0; i < 4; i++)
    sA[quad * 4 + i][w * 16 + m] = __float2half(acc2[i] * rs[i]);
  __syncthreads();

  if (threadIdx.x < 128) {
    int r = threadIdx.x >> 3, cc = threadIdx.x & 7;
    *reinterpret_cast<float4*>(z + (size_t)(blk0 + r) * 64 + cc * 8) =
        *reinterpret_cast<const float4*>(&sA[r][cc * 8]);
  }
}

// ---------------- gather-aggregate, width 64 half (wave per node) ------------
__global__ __launch_bounds__(256) void k_gath2(const __half* __restrict__ z,
                                               const int* __restrict__ rowptr,
                                               const int* __restrict__ deg,
                                               const int* __restrict__ srcIdx,
                                               const float* __restrict__ dinv,
                                               const float* __restrict__ b2,
                                               float* __restrict__ out) {
  int node = blockIdx.x * 4 + (threadIdx.x >> 6);
  if (node >= NN) return;
  int lane = threadIdx.x & 63;
  int g = lane >> 3;
  int c = lane & 7;
  int d = deg[node];
  int p = rowptr[node];
  size_t coff = (size_t)c * 8;
  float acc[8];
#pragma unroll
  for (int i = 0; i < 8; i++) acc[i] = 0.0f;

  for (int base = 0; base < d; base += 64) {
    int cnt = min(64, d - base);
    int my = (lane < cnt) ? srcIdx[p + base + lane] : 0;
    int k = 0;
    for (; k + 32 <= cnt; k += 32) {         // 32 neighbors, 4 loads in flight
      int s0 = __shfl(my, k + g);
      int s1 = __shfl(my, k + 8 + g);
      int s2 = __shfl(my, k + 16 + g);
      int s3 = __shfl(my, k + 24 + g);
      f16x8 v0 = *reinterpret_cast<const f16x8*>(z + (size_t)s0 * 64 + coff);
      f16x8 v1 = *reinterpret_cast<const f16x8*>(z + (size_t)s1 * 64 + coff);
      f16x8 v2 = *reinterpret_cast<const f16x8*>(z + (size_t)s2 * 64 + coff);
      f16x8 v3 = *reinterpret_cast<const f16x8*>(z + (size_t)s3 * 64 + coff);
#pragma unroll
      for (int i = 0; i < 8; i++) acc[i] += (float)v0[i];
#pragma unroll
      for (int i = 0; i < 8; i++) acc[i] += (float)v1[i];
#pragma unroll
      for (int i = 0; i < 8; i++) acc[i] += (float)v2[i];
#pragma unroll
      for (int i = 0; i < 8; i++) acc[i] += (float)v3[i];
    }
    for (; k + 16 <= cnt; k += 16) {         // 16 neighbors, 2 loads in flight
      int s0 = __shfl(my, k + g);
      int s1 = __shfl(my, k + 8 + g);
      f16x8 v0 = *reinterpret_cast<const f16x8*>(z + (size_t)s0 * 64 + coff);
      f16x8 v1 = *reinterpret_cast<const f16x8*>(z + (size_t)s1 * 64 + coff);
#pragma unroll
      for (int i = 0; i < 8; i++) acc[i] += (float)v0[i];
#pragma unroll
      for (int i = 0; i < 8; i++) acc[i] += (float)v1[i];
    }
    for (; k < cnt; k += 8) {                // remainder, predicated
      int idx = k + g;
      bool valid = idx < cnt;
      int s0 = __shfl(my, valid ? idx : 0);
      f16x8 v0 = *reinterpret_cast<const f16x8*>(z + (size_t)s0 * 64 + coff);
      if (valid) {
#pragma unroll
        for (int i = 0; i < 8; i++) acc[i] += (float)v0[i];
      }
    }
  }
#pragma unroll
  for (int i = 0; i < 8; i++) acc[i] += __shfl_xor(acc[i], 8);
#pragma unroll
  for (int i = 0; i < 8; i++) acc[i] += __shfl_xor(acc[i], 16);
#pragma unroll
  for (int i = 0; i < 8; i++) acc[i] += __shfl_xor(acc[i], 32);
  if (g == 0) {
    f16x8 sv = *reinterpret_cast<const f16x8*>(z + (size_t)node * 64 + coff);
    float s = dinv[node];
    const float4* b4 = reinterpret_cast<const float4*>(b2);
    float4 bv0 = b4[2 * c], bv1 = b4[2 * c + 1];
    float4 o0, o1;
    o0.x = (acc[0] + (float)sv[0]) * s + bv0.x;
    o0.y = (acc[1] + (float)sv[1]) * s + bv0.y;
    o0.z = (acc[2] + (float)sv[2]) * s + bv0.z;
    o0.w = (acc[3] + (float)sv[3]) * s + bv0.w;
    o1.x = (acc[4] + (float)sv[4]) * s + bv1.x;
    o1.y = (acc[5] + (float)sv[5]) * s + bv1.y;
    o1.z = (acc[6] + (float)sv[6]) * s + bv1.z;
    o1.w = (acc[7] + (float)sv[7]) * s + bv1.w;
    float4* op = reinterpret_cast<float4*>(out + (size_t)node * 64 + coff);
    op[0] = o0;
    op[1] = o1;
  }
}

extern "C" void kernel_launch(void* const* d_in, const int* in_sizes, int n_in,
                              void* d_out, int out_size, void* d_ws, size_t ws_size,
                              hipStream_t stream) {
  const float* x  = (const float*)d_in[0];
  const int*   ei = (const int*)d_in[1];  // [2, NE] row-major
  const int* rows = ei;
  const int* cols = ei + NE;
  const float* W1 = (const float*)d_in[3];
  const float* b1 = (const float*)d_in[4];
  const float* W2 = (const float*)d_in[5];
  const float* b2 = (const float*)d_in[6];
  float* out = (float*)d_out;

  char* base = (char*)d_ws;
  constexpr size_t MB = 1 << 20;
  int*      deg       = (int*)(base + 0 * MB);
  int*      rowptr    = (int*)(base + 1 * MB);
  float*    dinv      = (float*)(base + 2 * MB);
  int*      btot      = (int*)(base + 3 * MB);
  int*      bucketBase= (int*)(base + 3 * MB + 16 * 1024);
  __half*   Wt1       = (__half*)(base + 3 * MB + 64 * 1024);
  __half*   Wt2       = (__half*)(base + 3 * MB + 128 * 1024);
  int*      table     = (int*)(base + 4 * MB);
  int*      startOff  = (int*)(base + 5 * MB);
  unsigned* binned    = (unsigned*)(base + 6 * MB);
  int*      srcIdx    = (int*)(base + 13 * MB);
  __half*   y         = (__half*)(base + 20 * MB);    // 25.6 MB
  __half*   z         = (__half*)(base + 46 * MB);    // 12.8 MB

  k_histwt<<<NBLK + 96, 256, 0, stream>>>(cols, table, W1, W2, Wt1, Wt2);
  k_scanT<<<NB, 256, 0, stream>>>(table, startOff, btot);
  k_scatB<<<NBLK, 256, 0, stream>>>(rows, cols, startOff, btot, bucketBase,
                                    binned);
  k_fillb<<<NB, 256, 0, stream>>>(binned, bucketBase, btot, rowptr, deg, dinv,
                                  srcIdx, (const float4*)x, (float2*)y);
  k_fused<<<NN / 16, 256, 0, stream>>>(y, rowptr, deg, srcIdx, dinv,
                                       Wt1, b1, Wt2, z);
  k_gath2<<<(NN + 3) / 4, 256, 0, stream>>>(z, rowptr, deg, srcIdx, dinv, b2, out);
}